// Round 6
// baseline (1002.250 us; speedup 1.0000x reference)
//
#include <hip/hip_runtime.h>
#include <math.h>

#define N_NODES 100000
#define N_EDGES 3200000
#define H 10
#define S 12          // padded per-node stride (floats): 48B, float4-aligned
#define IN_DIM 16
#define NB 128        // nodes per bucket
#define NBKT 782      // ceil(N_NODES / NB)
#define BCAP 4608     // edge capacity per bucket (mean 4096, +8 sigma)
#define FTILE 8192    // edges per fill block (32 per thread)
#define NFB 391       // ceil(N_EDGES / FTILE)

typedef int nint4 __attribute__((ext_vector_type(4)));

// ============ bptr init: bucket write cursors at fixed-stride starts ============
__global__ __launch_bounds__(256) void k_binit(int* __restrict__ bptr)
{
    int i = blockIdx.x * 256 + threadIdx.x;
    if (i < NBKT) bptr[i] = i * BCAP;
}

// ---- bf16 pack (round-to-nearest-even) ----
__device__ __forceinline__ unsigned pack2bf(float a, float b)
{
    unsigned ua = __float_as_uint(a), ub = __float_as_uint(b);
    unsigned ra = (ua + 0x7FFFu + ((ua >> 16) & 1u)) >> 16;
    unsigned rb = (ub + 0x7FFFu + ((ub >> 16) & 1u)) >> 16;
    return ra | (rb << 16);
}

// ============ fill: tile-sorted scatter into bucket regions ============
// entry = 16B {bf16(a0,a1), bf16(a2,a3), row, col_local}
__global__ __launch_bounds__(256) void k_fill(const int* __restrict__ ei,
    const float* __restrict__ attr, int* __restrict__ bptr,
    nint4* __restrict__ entries)
{
    __shared__ int lcnt[NBKT];
    __shared__ int lbase[NBKT];
    int tid = threadIdx.x;
    int base = blockIdx.x * FTILE;
    for (int k = tid; k < NBKT; k += 256) lcnt[k] = 0;
    __syncthreads();
    int c[32];
    #pragma unroll
    for (int k = 0; k < 32; ++k) {
        int e = base + k * 256 + tid;
        c[k] = (e < N_EDGES) ? ei[N_EDGES + e] : -1;
        if (c[k] >= 0) atomicAdd(&lcnt[c[k] >> 7], 1);
    }
    __syncthreads();
    for (int k = tid; k < NBKT; k += 256) {
        int n = lcnt[k];
        lbase[k] = n ? atomicAdd(&bptr[k], n) : 0;   // absolute entry index
        lcnt[k] = 0;
    }
    __syncthreads();
    #pragma unroll
    for (int k = 0; k < 32; ++k) {
        if (c[k] < 0) continue;
        int e = base + k * 256 + tid;
        int b = c[k] >> 7;
        int slot = atomicAdd(&lcnt[b], 1);
        int dest = lbase[b] + slot;
        if (dest < (b + 1) * BCAP) {                  // overflow guard (never fires)
            float4 a = ((const float4*)attr)[e];
            nint4 v;
            v.x = (int)pack2bf(a.x, a.y);
            v.y = (int)pack2bf(a.z, a.w);
            v.z = ei[e];
            v.w = c[k] & (NB - 1);
            __builtin_nontemporal_store(v, &entries[dest]);
        }
    }
}

// ============ shared helper: ew from packed attr ============
__device__ __forceinline__ void ew_from_packed(int px, int py,
    const float* sW1, const float* sW2, float ew[H])
{
    float ax = __uint_as_float(((unsigned)px) << 16);
    float ay = __uint_as_float(((unsigned)px) & 0xffff0000u);
    float az = __uint_as_float(((unsigned)py) << 16);
    float aw = __uint_as_float(((unsigned)py) & 0xffff0000u);
    float tt[H];
    #pragma unroll
    for (int j = 0; j < H; ++j)
        tt[j] = fmaxf(fmaf(ax, sW1[j], fmaf(ay, sW1[H+j],
                      fmaf(az, sW1[2*H+j], aw*sW1[3*H+j]))), 0.f);
    #pragma unroll
    for (int ch = 0; ch < H; ++ch) {
        float v = 0.f;
        #pragma unroll
        for (int j = 0; j < H; ++j) v = fmaf(tt[j], sW2[j*H + ch], v);
        ew[ch] = fmaxf(v, 0.f);
    }
}

// ============ deg pass: LDS-accumulate ew sums; epilogue computes
//  x_ = x@iW + ib ; dinv = rsqrt(1+deg) ; u0 = dinv*relu(x_)*gw0 ============
__global__ __launch_bounds__(256) void k_deg(const nint4* __restrict__ entries,
    const int* __restrict__ bptr,
    const float* __restrict__ W1, const float* __restrict__ W2,
    const float* __restrict__ x, const float* __restrict__ iW,
    const float* __restrict__ ib, const float* __restrict__ gw0,
    float* __restrict__ x_, float* __restrict__ dinv, float* __restrict__ u)
{
    __shared__ float sW1[4*H], sW2[H*H], siW[IN_DIM*H], sib[H], sgw[H];
    __shared__ float acc[NB*H];
    int tid = threadIdx.x;
    for (int k = tid; k < 4*H; k += 256) sW1[k] = W1[k];
    for (int k = tid; k < H*H; k += 256) sW2[k] = W2[k];
    for (int k = tid; k < IN_DIM*H; k += 256) siW[k] = iW[k];
    if (tid < H) sib[tid] = ib[tid];
    if (tid >= 32 && tid < 32+H) sgw[tid-32] = gw0[tid-32];
    for (int k = tid; k < NB*H; k += 256) acc[k] = 0.f;
    __syncthreads();
    int b = blockIdx.x;
    int st = b * BCAP;
    int en = min(bptr[b], st + BCAP);
    for (int e = st + tid; e < en; e += 256) {
        nint4 ent = entries[e];
        float ew[H];
        ew_from_packed(ent.x, ent.y, sW1, sW2, ew);
        float* ac = &acc[ent.w * H];
        #pragma unroll
        for (int ch = 0; ch < H; ++ch) atomicAdd(&ac[ch], ew[ch]);
    }
    __syncthreads();
    int node = b * NB + tid;
    if (tid < NB && node < N_NODES) {
        const float4* xv4 = (const float4*)(x + (size_t)node * IN_DIM);
        float xi[IN_DIM];
        float4 a0 = xv4[0], a1 = xv4[1], a2 = xv4[2], a3 = xv4[3];
        xi[0]=a0.x; xi[1]=a0.y; xi[2]=a0.z; xi[3]=a0.w;
        xi[4]=a1.x; xi[5]=a1.y; xi[6]=a1.z; xi[7]=a1.w;
        xi[8]=a2.x; xi[9]=a2.y; xi[10]=a2.z; xi[11]=a2.w;
        xi[12]=a3.x; xi[13]=a3.y; xi[14]=a3.z; xi[15]=a3.w;
        float xb[H], dv[H], uu[H];
        #pragma unroll
        for (int j = 0; j < H; ++j) {
            float a = sib[j];
            #pragma unroll
            for (int k = 0; k < IN_DIM; ++k) a = fmaf(xi[k], siW[k*H + j], a);
            xb[j] = a;
        }
        const float* ac = &acc[tid * H];
        #pragma unroll
        for (int ch = 0; ch < H; ++ch) {
            float di = rsqrtf(1.0f + ac[ch]);
            dv[ch] = di;
            uu[ch] = di * fmaxf(xb[ch], 0.f) * sgw[ch];
        }
        float* xd = x_   + (size_t)node * S;
        float* dd = dinv + (size_t)node * S;
        float* ud = u    + (size_t)node * S;
        *(float4*)(xd+0) = make_float4(xb[0],xb[1],xb[2],xb[3]);
        *(float4*)(xd+4) = make_float4(xb[4],xb[5],xb[6],xb[7]);
        *(float4*)(xd+8) = make_float4(xb[8],xb[9],0.f,0.f);
        *(float4*)(dd+0) = make_float4(dv[0],dv[1],dv[2],dv[3]);
        *(float4*)(dd+4) = make_float4(dv[4],dv[5],dv[6],dv[7]);
        *(float4*)(dd+8) = make_float4(dv[8],dv[9],0.f,0.f);
        *(float4*)(ud+0) = make_float4(uu[0],uu[1],uu[2],uu[3]);
        *(float4*)(ud+4) = make_float4(uu[4],uu[5],uu[6],uu[7]);
        *(float4*)(ud+8) = make_float4(uu[8],uu[9],0.f,0.f);
    }
}

// ============ fused layer: LDS-accumulate + per-node update ============
template<int LAST>
__global__ __launch_bounds__(256) void k_layer(const nint4* __restrict__ entries,
    const int* __restrict__ bptr,
    const float* __restrict__ W1, const float* __restrict__ W2,
    const float* __restrict__ x_, const float* __restrict__ dinv,
    const float* __restrict__ uin, const float* __restrict__ lin,
    const float* __restrict__ gw_next, const float* __restrict__ gb,
    const float* __restrict__ oW, float* __restrict__ uout, float* __restrict__ out)
{
    __shared__ float sW1[4*H], sW2[H*H], slin[2*H*H], sgw[H], sgb[H], soW[4*H];
    __shared__ float acc[NB*H];
    int tid = threadIdx.x;
    for (int k = tid; k < 4*H; k += 256) sW1[k] = W1[k];
    for (int k = tid; k < H*H; k += 256) sW2[k] = W2[k];
    for (int k = tid; k < 2*H*H; k += 256) slin[k] = lin[k];
    if (tid < H) sgb[tid] = gb[tid];
    if (LAST) { if (tid >= 32 && tid < 32+4*H) soW[tid-32] = oW[tid-32]; }
    else      { if (tid >= 32 && tid < 32+H)   sgw[tid-32] = gw_next[tid-32]; }
    for (int k = tid; k < NB*H; k += 256) acc[k] = 0.f;
    __syncthreads();
    int b = blockIdx.x;
    int st = b * BCAP;
    int en = min(bptr[b], st + BCAP);
    for (int e = st + tid; e < en; e += 256) {
        nint4 ent = entries[e];
        const float4* up = (const float4*)(uin + (size_t)ent.z * S);
        float4 u0 = up[0], u1 = up[1], u2 = up[2];
        float ew[H];
        ew_from_packed(ent.x, ent.y, sW1, sW2, ew);
        float ur[H];
        ur[0]=u0.x; ur[1]=u0.y; ur[2]=u0.z; ur[3]=u0.w;
        ur[4]=u1.x; ur[5]=u1.y; ur[6]=u1.z; ur[7]=u1.w;
        ur[8]=u2.x; ur[9]=u2.y;
        float* ac = &acc[ent.w * H];
        #pragma unroll
        for (int ch = 0; ch < H; ++ch) atomicAdd(&ac[ch], ew[ch] * ur[ch]);
    }
    __syncthreads();
    int node = b * NB + tid;
    if (tid < NB && node < N_NODES) {
        const float* xi = x_   + (size_t)node * S;
        const float* di = dinv + (size_t)node * S;
        const float* ui = uin  + (size_t)node * S;
        const float* ac = &acc[tid * H];
        float xv[H], agg[H];
        #pragma unroll
        for (int ch = 0; ch < H; ++ch) {
            xv[ch] = xi[ch];
            agg[ch] = di[ch] * (ac[ch] + ui[ch]) + sgb[ch];  // self-loop folded in
        }
        float h[H];
        #pragma unroll
        for (int j = 0; j < H; ++j) {
            float a = xv[j];                                  // residual
            #pragma unroll
            for (int k = 0; k < H; ++k) a = fmaf(xv[k], slin[k*H + j], a);
            #pragma unroll
            for (int k = 0; k < H; ++k) a = fmaf(agg[k], slin[(H+k)*H + j], a);
            h[j] = a;
        }
        if (!LAST) {
            float un[H];
            #pragma unroll
            for (int ch = 0; ch < H; ++ch)
                un[ch] = di[ch] * fmaxf(h[ch], 0.f) * sgw[ch];
            float* ud = uout + (size_t)node * S;
            *(float4*)(ud+0) = make_float4(un[0],un[1],un[2],un[3]);
            *(float4*)(ud+4) = make_float4(un[4],un[5],un[6],un[7]);
            *(float4*)(ud+8) = make_float4(un[8],un[9],0.f,0.f);
        } else {
            float z0 = 0.f, z1 = 0.f;
            #pragma unroll
            for (int k = 0; k < H; ++k) { z0 = fmaf(xv[k], soW[2*k],   z0);
                                          z1 = fmaf(xv[k], soW[2*k+1], z1); }
            #pragma unroll
            for (int k = 0; k < H; ++k) { float hr = fmaxf(h[k], 0.f);
                                          z0 = fmaf(hr, soW[2*(H+k)],   z0);
                                          z1 = fmaf(hr, soW[2*(H+k)+1], z1); }
            out[node] = 1.0f / (1.0f + expf(z0 - z1));
        }
    }
}

extern "C" void kernel_launch(void* const* d_in, const int* in_sizes, int n_in,
                              void* d_out, int out_size, void* d_ws, size_t ws_size,
                              hipStream_t stream)
{
    const float* x     = (const float*)d_in[0];
    const int*   ei    = (const int*)  d_in[1];
    const float* attr  = (const float*)d_in[2];
    const float* ew_W1 = (const float*)d_in[3];
    const float* ew_W2 = (const float*)d_in[4];
    const float* iW    = (const float*)d_in[5];
    const float* ib    = (const float*)d_in[6];
    const float* gcn_w = (const float*)d_in[7];
    const float* gcn_b = (const float*)d_in[8];
    const float* lin_W = (const float*)d_in[9];
    const float* oW    = (const float*)d_in[10];
    float* out = (float*)d_out;
    char* ws = (char*)d_ws;

    size_t o = 0;
    nint4* entries = (nint4*)(ws + o); o += (size_t)NBKT * BCAP * 16;      // 57.7 MB
    float* x_   = (float*)(ws + o); o += (size_t)N_NODES * S * 4;          // 4.8 MB
    float* dinv = (float*)(ws + o); o += (size_t)N_NODES * S * 4;
    float* u_a  = (float*)(ws + o); o += (size_t)N_NODES * S * 4;
    float* u_b  = (float*)(ws + o); o += (size_t)N_NODES * S * 4;
    int* bptr   = (int*)(ws + o); o += (size_t)NBKT * 4;

    dim3 blk(256);

    k_binit<<<(NBKT + 255) / 256, blk, 0, stream>>>(bptr);
    k_fill <<<NFB, blk, 0, stream>>>(ei, attr, bptr, entries);
    k_deg  <<<NBKT, blk, 0, stream>>>(entries, bptr, ew_W1, ew_W2,
                                      x, iW, ib, gcn_w, x_, dinv, u_a);
    // layer 0: reads u_a, writes u_b
    k_layer<0><<<NBKT, blk, 0, stream>>>(entries, bptr, ew_W1, ew_W2,
        x_, dinv, u_a, lin_W + 0*2*H*H, gcn_w + 1*H, gcn_b + 0*H, oW, u_b, out);
    // layer 1: reads u_b, writes u_a
    k_layer<0><<<NBKT, blk, 0, stream>>>(entries, bptr, ew_W1, ew_W2,
        x_, dinv, u_b, lin_W + 1*2*H*H, gcn_w + 2*H, gcn_b + 1*H, oW, u_a, out);
    // layer 2: reads u_a, writes out
    k_layer<1><<<NBKT, blk, 0, stream>>>(entries, bptr, ew_W1, ew_W2,
        x_, dinv, u_a, lin_W + 2*2*H*H, nullptr, gcn_b + 2*H, oW, nullptr, out);
}